// Round 1
// baseline (580.551 us; speedup 1.0000x reference)
//
#include <hip/hip_runtime.h>
#include <math.h>

#define HW_   40000      // H*W = 200*200
#define NQ_   40000
#define IMGW  200
#define IMGH  200

// ---------------------------------------------------------------------------
// Tiled fp32 GEMM: 64x64 tile, K-step 16, 256 threads, 4x4 per thread.
// As stored transposed (k-major) with +4 pad; Bs natural with +4 pad.
// ---------------------------------------------------------------------------

#define GEMM_PROLOGUE()                                                        \
  __shared__ float As[16][68];                                                 \
  __shared__ float Bs[16][68];                                                 \
  const int t  = threadIdx.x;                                                  \
  const int tx = t & 15, ty = t >> 4;                                          \
  const int m0 = blockIdx.y * 64;                                              \
  const int n0 = blockIdx.x * 64;                                              \
  const int lar = t >> 2;          /* A row 0..63 */                           \
  const int lac = (t & 3) * 4;     /* A col 0..12 */                           \
  const int lbr = t >> 4;          /* B row 0..15 */                           \
  const int lbc = (t & 15) * 4;    /* B col 0..60 */                           \
  float acc[4][4] = {};

#define GEMM_STAGE_AND_COMPUTE(AV, BV)                                         \
  __syncthreads();                                                             \
  As[lac + 0][lar] = AV.x;                                                     \
  As[lac + 1][lar] = AV.y;                                                     \
  As[lac + 2][lar] = AV.z;                                                     \
  As[lac + 3][lar] = AV.w;                                                     \
  *(float4*)&Bs[lbr][lbc] = BV;                                                \
  __syncthreads();                                                             \
  _Pragma("unroll")                                                            \
  for (int kk = 0; kk < 16; ++kk) {                                            \
    float4 a = *(const float4*)&As[kk][ty * 4];                                \
    float4 b = *(const float4*)&Bs[kk][tx * 4];                                \
    acc[0][0] = fmaf(a.x, b.x, acc[0][0]);                                     \
    acc[0][1] = fmaf(a.x, b.y, acc[0][1]);                                     \
    acc[0][2] = fmaf(a.x, b.z, acc[0][2]);                                     \
    acc[0][3] = fmaf(a.x, b.w, acc[0][3]);                                     \
    acc[1][0] = fmaf(a.y, b.x, acc[1][0]);                                     \
    acc[1][1] = fmaf(a.y, b.y, acc[1][1]);                                     \
    acc[1][2] = fmaf(a.y, b.z, acc[1][2]);                                     \
    acc[1][3] = fmaf(a.y, b.w, acc[1][3]);                                     \
    acc[2][0] = fmaf(a.z, b.x, acc[2][0]);                                     \
    acc[2][1] = fmaf(a.z, b.y, acc[2][1]);                                     \
    acc[2][2] = fmaf(a.z, b.z, acc[2][2]);                                     \
    acc[2][3] = fmaf(a.z, b.w, acc[2][3]);                                     \
    acc[3][0] = fmaf(a.w, b.x, acc[3][0]);                                     \
    acc[3][1] = fmaf(a.w, b.y, acc[3][1]);                                     \
    acc[3][2] = fmaf(a.w, b.z, acc[3][2]);                                     \
    acc[3][3] = fmaf(a.w, b.w, acc[3][3]);                                     \
  }

// ---- Kernel 1: vproj = value @ W_v + b_v, stored as (nbq, h, pix, hd) -----
__global__ __launch_bounds__(256) void gemm_vproj_kernel(
    const float* __restrict__ A,    // value 80000 x 256
    const float* __restrict__ B,    // W_v 256 x 256
    const float* __restrict__ bias, // b_v 256
    float* __restrict__ vws)        // (2, 8, 40000, 32)
{
  GEMM_PROLOGUE();
  for (int kt = 0; kt < 256; kt += 16) {
    float4 av = *(const float4*)&A[(size_t)(m0 + lar) * 256 + kt + lac];
    float4 bv = *(const float4*)&B[(size_t)(kt + lbr) * 256 + n0 + lbc];
    GEMM_STAGE_AND_COMPUTE(av, bv);
  }
  const int ncol0 = n0 + tx * 4;
  const int h  = ncol0 >> 5;
  const int hd = ncol0 & 31;
  const float4 bb = *(const float4*)&bias[ncol0];
#pragma unroll
  for (int i = 0; i < 4; ++i) {
    int m   = m0 + ty * 4 + i;
    int nbq = m / HW_;
    int pix = m - nbq * HW_;
    float4 c;
    c.x = acc[i][0] + bb.x;
    c.y = acc[i][1] + bb.y;
    c.z = acc[i][2] + bb.z;
    c.w = acc[i][3] + bb.w;
    *(float4*)&vws[(((size_t)(nbq * 8 + h) * HW_ + pix) << 5) + hd] = c;
  }
}

// ---- Kernel 2: [off | aw] = qe @ [W_so | W_aw] + bias, qe = [value0|query] -
__global__ __launch_bounds__(256) void gemm_offaw_kernel(
    const float* __restrict__ value,  // first 40000 rows used (bev 0)
    const float* __restrict__ query,
    const float* __restrict__ Wso,    // 512 x 128
    const float* __restrict__ Waw,    // 512 x 64
    const float* __restrict__ bso,
    const float* __restrict__ baw,
    float* __restrict__ off_ws,       // 40000 x 128
    float* __restrict__ aw_ws)        // 40000 x 64
{
  GEMM_PROLOGUE();
  for (int kt = 0; kt < 512; kt += 16) {
    const float* Ap = (kt < 256) ? value : query;
    const int ka = (kt < 256) ? kt : (kt - 256);
    float4 av = *(const float4*)&Ap[(size_t)(m0 + lar) * 256 + ka + lac];
    const int gk = kt + lbr;
    const int nc = n0 + lbc;
    float4 bv = (n0 < 128) ? *(const float4*)&Wso[(size_t)gk * 128 + nc]
                           : *(const float4*)&Waw[(size_t)gk * 64 + (nc - 128)];
    GEMM_STAGE_AND_COMPUTE(av, bv);
  }
  const int ncol0 = n0 + tx * 4;
  if (n0 < 128) {
    const float4 bb = *(const float4*)&bso[ncol0];
#pragma unroll
    for (int i = 0; i < 4; ++i) {
      int m = m0 + ty * 4 + i;
      float4 c;
      c.x = acc[i][0] + bb.x;
      c.y = acc[i][1] + bb.y;
      c.z = acc[i][2] + bb.z;
      c.w = acc[i][3] + bb.w;
      *(float4*)&off_ws[(size_t)m * 128 + ncol0] = c;
    }
  } else {
    const float4 bb = *(const float4*)&baw[ncol0 - 128];
#pragma unroll
    for (int i = 0; i < 4; ++i) {
      int m = m0 + ty * 4 + i;
      float4 c;
      c.x = acc[i][0] + bb.x;
      c.y = acc[i][1] + bb.y;
      c.z = acc[i][2] + bb.z;
      c.w = acc[i][3] + bb.w;
      *(float4*)&aw_ws[(size_t)m * 64 + (ncol0 - 128)] = c;
    }
  }
}

// ---- Kernel 3: softmax + locations + bilinear deformable sampling ---------
// One block per query q, 256 threads: h = t>>5, hd = t&31.
// ms[q, h*32+hd] = 0.5 * sum_{nbq,p} softmax(aw)[p] * bilinear(v[nbq,h], x, y)
__global__ __launch_bounds__(256) void deform_attn_kernel(
    const float* __restrict__ vws,     // (2,8,40000,32)
    const float* __restrict__ off_ws,  // (40000,128)
    const float* __restrict__ aw_ws,   // (40000,64)
    const float* __restrict__ ref,     // (40000,2)
    float* __restrict__ ms)            // (40000,256)
{
  const int q  = blockIdx.x;
  const int t  = threadIdx.x;
  const int h  = t >> 5;
  const int hd = t & 31;
  const float rx = ref[2 * q + 0] * (float)IMGW - 0.5f;
  const float ry = ref[2 * q + 1] * (float)IMGH - 0.5f;
  float acc = 0.0f;
#pragma unroll
  for (int nbq = 0; nbq < 2; ++nbq) {
    const int g = h * 2 + nbq;
    // softmax over the 4 points (broadcast load within the 32-lane group)
    const float4 a4 = *(const float4*)&aw_ws[(size_t)q * 64 + g * 4];
    float mx = fmaxf(fmaxf(a4.x, a4.y), fmaxf(a4.z, a4.w));
    float e0 = __expf(a4.x - mx), e1 = __expf(a4.y - mx);
    float e2 = __expf(a4.z - mx), e3 = __expf(a4.w - mx);
    float inv = 1.0f / (e0 + e1 + e2 + e3);
    float w4[4] = {e0 * inv, e1 * inv, e2 * inv, e3 * inv};
    const float4 o01 = *(const float4*)&off_ws[(size_t)q * 128 + g * 8];
    const float4 o23 = *(const float4*)&off_ws[(size_t)q * 128 + g * 8 + 4];
    float ox[4] = {o01.x, o01.z, o23.x, o23.z};
    float oy[4] = {o01.y, o01.w, o23.y, o23.w};
    const float* vbase = vws + ((size_t)(nbq * 8 + h) * HW_) * 32 + hd;
#pragma unroll
    for (int p = 0; p < 4; ++p) {
      float x = rx + ox[p];
      float y = ry + oy[p];
      float xf = floorf(x), yf = floorf(y);
      int   x0 = (int)xf,   y0 = (int)yf;
      float lx = x - xf,    ly = y - yf;
      int   x1 = x0 + 1,    y1 = y0 + 1;
      float w00 = (1.0f - lx) * (1.0f - ly);
      float w01 = lx * (1.0f - ly);
      float w10 = (1.0f - lx) * ly;
      float w11 = lx * ly;
      if (x0 < 0 || x0 >= IMGW) { w00 = 0.0f; w10 = 0.0f; }
      if (x1 < 0 || x1 >= IMGW) { w01 = 0.0f; w11 = 0.0f; }
      if (y0 < 0 || y0 >= IMGH) { w00 = 0.0f; w01 = 0.0f; }
      if (y1 < 0 || y1 >= IMGH) { w10 = 0.0f; w11 = 0.0f; }
      int xc0 = min(max(x0, 0), IMGW - 1), xc1 = min(max(x1, 0), IMGW - 1);
      int yc0 = min(max(y0, 0), IMGH - 1), yc1 = min(max(y1, 0), IMGH - 1);
      float v00 = vbase[(size_t)(yc0 * IMGW + xc0) * 32];
      float v01 = vbase[(size_t)(yc0 * IMGW + xc1) * 32];
      float v10 = vbase[(size_t)(yc1 * IMGW + xc0) * 32];
      float v11 = vbase[(size_t)(yc1 * IMGW + xc1) * 32];
      float s = w00 * v00 + w01 * v01 + w10 * v10 + w11 * v11;
      acc = fmaf(w4[p], s, acc);
    }
  }
  ms[(size_t)q * 256 + t] = 0.5f * acc;  // mean over NBQ=2
}

// ---- Kernel 4: out = ms @ W_o + b_o + query -------------------------------
__global__ __launch_bounds__(256) void gemm_out_kernel(
    const float* __restrict__ A,   // ms 40000 x 256
    const float* __restrict__ B,   // W_o 256 x 256
    const float* __restrict__ bias,
    const float* __restrict__ query,
    float* __restrict__ out)
{
  GEMM_PROLOGUE();
  for (int kt = 0; kt < 256; kt += 16) {
    float4 av = *(const float4*)&A[(size_t)(m0 + lar) * 256 + kt + lac];
    float4 bv = *(const float4*)&B[(size_t)(kt + lbr) * 256 + n0 + lbc];
    GEMM_STAGE_AND_COMPUTE(av, bv);
  }
  const int ncol0 = n0 + tx * 4;
  const float4 bb = *(const float4*)&bias[ncol0];
#pragma unroll
  for (int i = 0; i < 4; ++i) {
    int m = m0 + ty * 4 + i;
    float4 qv = *(const float4*)&query[(size_t)m * 256 + ncol0];
    float4 c;
    c.x = acc[i][0] + bb.x + qv.x;
    c.y = acc[i][1] + bb.y + qv.y;
    c.z = acc[i][2] + bb.z + qv.z;
    c.w = acc[i][3] + bb.w + qv.w;
    *(float4*)&out[(size_t)m * 256 + ncol0] = c;
  }
}

extern "C" void kernel_launch(void* const* d_in, const int* in_sizes, int n_in,
                              void* d_out, int out_size, void* d_ws, size_t ws_size,
                              hipStream_t stream) {
  const float* query = (const float*)d_in[0];   // (1, 40000, 256)
  const float* value = (const float*)d_in[1];   // (1, 80000, 256)
  const float* ref   = (const float*)d_in[2];   // (1, 40000, 1, 2)
  // d_in[3] spatial_shapes == [[200,200]], hardcoded
  const float* Wv  = (const float*)d_in[4];
  const float* bv  = (const float*)d_in[5];
  const float* Wso = (const float*)d_in[6];
  const float* bso = (const float*)d_in[7];
  const float* Waw = (const float*)d_in[8];
  const float* baw = (const float*)d_in[9];
  const float* Wo  = (const float*)d_in[10];
  const float* bo  = (const float*)d_in[11];
  float* out = (float*)d_out;

  float* vws    = (float*)d_ws;                       // 2*8*40000*32 = 20.48M floats
  float* off_ws = vws + (size_t)2 * 8 * HW_ * 32;     // 40000*128     =  5.12M
  float* aw_ws  = off_ws + (size_t)NQ_ * 128;         // 40000*64      =  2.56M
  float* ms     = aw_ws + (size_t)NQ_ * 64;           // 40000*256     = 10.24M
  // total 38.4M floats = 153.6 MB of d_ws

  gemm_vproj_kernel<<<dim3(4, 1250), 256, 0, stream>>>(value, Wv, bv, vws);
  gemm_offaw_kernel<<<dim3(3, 625), 256, 0, stream>>>(value, query, Wso, Waw,
                                                      bso, baw, off_ws, aw_ws);
  deform_attn_kernel<<<dim3(NQ_), 256, 0, stream>>>(vws, off_ws, aw_ws, ref, ms);
  gemm_out_kernel<<<dim3(4, 625), 256, 0, stream>>>(ms, Wo, bo, query, out);
}

// Round 2
// 364.740 us; speedup vs baseline: 1.5917x; 1.5917x over previous
//
#include <hip/hip_runtime.h>
#include <math.h>

#define HW_   40000      // H*W = 200*200
#define NQ_   40000
#define IMGW  200
#define IMGH  200

typedef __bf16 bf16;
typedef __attribute__((ext_vector_type(4))) __bf16 bf16x4;
typedef __attribute__((ext_vector_type(8))) __bf16 bf16x8;
typedef __attribute__((ext_vector_type(4))) float f32x4;

// ---------------------------------------------------------------------------
// Cast+transpose weights: Bt[n][k] = (bf16) B[k][n]. Tiny (<256K elems).
// ---------------------------------------------------------------------------
__global__ __launch_bounds__(256) void cast_transpose_kernel(
    const float* __restrict__ B, bf16* __restrict__ Bt, int K, int N, int ldt)
{
  int idx = blockIdx.x * 256 + threadIdx.x;
  if (idx >= K * N) return;
  int k = idx / N, n = idx - k * N;
  Bt[(size_t)n * ldt + k] = (bf16)B[idx];
}

// ---------------------------------------------------------------------------
// MFMA bf16 GEMM: C[M,N] = A[M,K] (fp32, cast in staging) @ Bt[N,K] (bf16).
// 128x128 tile, BK=32, 256 threads = 4 waves in 2x2, each wave 64x64 via
// 4x4 grid of v_mfma_f32_16x16x32_bf16. LDS rows padded to 40 bf16 (80 B,
// 16B-aligned, conflict-light).
// A-frag: A[m=lane&15][k=quad*8+j]; B-frag: B^T[n=lane&15][k=quad*8+j];
// D: col=lane&15, row=quad*4+reg   (verified layouts per guide §3).
// MODE 0: vproj -> bf16 (nbq,h,pix,hd) layout, +bias0
// MODE 1: offaw -> off_ws (n<128,+bias0) / aw_ws (128<=n<192,+bias1)
// MODE 2: out   -> fp32 +bias0 +resid
// ---------------------------------------------------------------------------
template<int KT, int MODE>
__global__ __launch_bounds__(256) void mfma_gemm_kernel(
    const float* __restrict__ A0, const float* __restrict__ A1,
    const bf16* __restrict__ Bt,
    const float* __restrict__ bias0, const float* __restrict__ bias1,
    const float* __restrict__ resid,
    void* __restrict__ outp, void* __restrict__ outp2,
    int M, int N)
{
  __shared__ bf16 As[128][40];
  __shared__ bf16 Bs[128][40];
  const int t    = threadIdx.x;
  const int m0   = blockIdx.y * 128;
  const int n0   = blockIdx.x * 128;
  const int w    = t >> 6;
  const int lane = t & 63;
  const int quad = lane >> 4;
  const int l16  = lane & 15;
  const int wm   = (w & 1) * 64;
  const int wn   = (w >> 1) * 64;

  f32x4 acc[4][4] = {};

  const int sa_row = t >> 3;        // 0..31 (+ i*32)
  const int sa_k   = (t & 7) * 4;   // 0,4,...,28
  const int sb_row = t >> 2;        // 0..63 (+ i*64)
  const int sb_k   = (t & 3) * 8;   // 0,8,16,24

  for (int kt = 0; kt < KT; kt += 32) {
    __syncthreads();
    // ---- stage A (fp32 -> bf16) ----
#pragma unroll
    for (int i = 0; i < 4; ++i) {
      int m  = i * 32 + sa_row;
      int gm = m0 + m; if (gm >= M) gm = M - 1;
      int gk = kt + sa_k;
      const float* Ap;
      int col;
      if (KT == 512) { Ap = (gk < 256) ? A0 : A1; col = gk & 255; }
      else           { Ap = A0; col = gk; }
      float4 av = *(const float4*)&Ap[(size_t)gm * 256 + col];
      bf16x4 bv = { (bf16)av.x, (bf16)av.y, (bf16)av.z, (bf16)av.w };
      *(bf16x4*)&As[m][sa_k] = bv;
    }
    // ---- stage B (bf16, already transposed) ----
#pragma unroll
    for (int i = 0; i < 2; ++i) {
      int n  = i * 64 + sb_row;
      int gn = n0 + n; if (gn >= N) gn = N - 1;
      float4 bv = *(const float4*)&Bt[(size_t)gn * KT + kt + sb_k];
      *(float4*)&Bs[n][sb_k] = bv;
    }
    __syncthreads();
    // ---- fragments + MFMA ----
    bf16x8 af[4], bfr[4];
#pragma unroll
    for (int x = 0; x < 4; ++x) {
      af[x]  = *(const bf16x8*)&As[wm + x * 16 + l16][quad * 8];
      bfr[x] = *(const bf16x8*)&Bs[wn + x * 16 + l16][quad * 8];
    }
#pragma unroll
    for (int mt = 0; mt < 4; ++mt)
#pragma unroll
      for (int nt = 0; nt < 4; ++nt)
        acc[mt][nt] = __builtin_amdgcn_mfma_f32_16x16x32_bf16(
            af[mt], bfr[nt], acc[mt][nt], 0, 0, 0);
  }

  // ---- epilogue ----
#pragma unroll
  for (int mt = 0; mt < 4; ++mt) {
#pragma unroll
    for (int r = 0; r < 4; ++r) {
      const int gm = m0 + wm + mt * 16 + quad * 4 + r;
      if (gm >= M) continue;
#pragma unroll
      for (int nt = 0; nt < 4; ++nt) {
        const int gn = n0 + wn + nt * 16 + l16;
        float v = acc[mt][nt][r];
        if (MODE == 0) {
          int nbq = (gm >= HW_) ? 1 : 0;
          int pix = gm - nbq * HW_;
          int h = gn >> 5, hd = gn & 31;
          ((bf16*)outp)[(((size_t)(nbq * 8 + h) * HW_ + pix) << 5) + hd] =
              (bf16)(v + bias0[gn]);
        } else if (MODE == 1) {
          if (gn < 128)
            ((float*)outp)[(size_t)gm * 128 + gn] = v + bias0[gn];
          else if (gn < 192)
            ((float*)outp2)[(size_t)gm * 64 + (gn - 128)] = v + bias1[gn - 128];
        } else {
          ((float*)outp)[(size_t)gm * 256 + gn] =
              v + bias0[gn] + resid[(size_t)gm * 256 + gn];
        }
      }
    }
  }
}

// ---- softmax + locations + bilinear deformable sampling -------------------
// One block per query q, 256 threads: h = t>>5, hd = t&31. vws is bf16.
__global__ __launch_bounds__(256) void deform_attn_kernel(
    const bf16*  __restrict__ vws,     // (2,8,40000,32) bf16
    const float* __restrict__ off_ws,  // (40000,128)
    const float* __restrict__ aw_ws,   // (40000,64)
    const float* __restrict__ ref,     // (40000,2)
    float* __restrict__ ms)            // (40000,256)
{
  const int q  = blockIdx.x;
  const int t  = threadIdx.x;
  const int h  = t >> 5;
  const int hd = t & 31;
  const float rx = ref[2 * q + 0] * (float)IMGW - 0.5f;
  const float ry = ref[2 * q + 1] * (float)IMGH - 0.5f;
  float acc = 0.0f;
#pragma unroll
  for (int nbq = 0; nbq < 2; ++nbq) {
    const int g = h * 2 + nbq;
    const float4 a4 = *(const float4*)&aw_ws[(size_t)q * 64 + g * 4];
    float mx = fmaxf(fmaxf(a4.x, a4.y), fmaxf(a4.z, a4.w));
    float e0 = __expf(a4.x - mx), e1 = __expf(a4.y - mx);
    float e2 = __expf(a4.z - mx), e3 = __expf(a4.w - mx);
    float inv = 1.0f / (e0 + e1 + e2 + e3);
    float w4[4] = {e0 * inv, e1 * inv, e2 * inv, e3 * inv};
    const float4 o01 = *(const float4*)&off_ws[(size_t)q * 128 + g * 8];
    const float4 o23 = *(const float4*)&off_ws[(size_t)q * 128 + g * 8 + 4];
    float ox[4] = {o01.x, o01.z, o23.x, o23.z};
    float oy[4] = {o01.y, o01.w, o23.y, o23.w};
    const bf16* vbase = vws + (((size_t)(nbq * 8 + h) * HW_) << 5) + hd;
#pragma unroll
    for (int p = 0; p < 4; ++p) {
      float x = rx + ox[p];
      float y = ry + oy[p];
      float xf = floorf(x), yf = floorf(y);
      int   x0 = (int)xf,   y0 = (int)yf;
      float lx = x - xf,    ly = y - yf;
      int   x1 = x0 + 1,    y1 = y0 + 1;
      float w00 = (1.0f - lx) * (1.0f - ly);
      float w01 = lx * (1.0f - ly);
      float w10 = (1.0f - lx) * ly;
      float w11 = lx * ly;
      if (x0 < 0 || x0 >= IMGW) { w00 = 0.0f; w10 = 0.0f; }
      if (x1 < 0 || x1 >= IMGW) { w01 = 0.0f; w11 = 0.0f; }
      if (y0 < 0 || y0 >= IMGH) { w00 = 0.0f; w01 = 0.0f; }
      if (y1 < 0 || y1 >= IMGH) { w10 = 0.0f; w11 = 0.0f; }
      int xc0 = min(max(x0, 0), IMGW - 1), xc1 = min(max(x1, 0), IMGW - 1);
      int yc0 = min(max(y0, 0), IMGH - 1), yc1 = min(max(y1, 0), IMGH - 1);
      float v00 = (float)vbase[(size_t)(yc0 * IMGW + xc0) << 5];
      float v01 = (float)vbase[(size_t)(yc0 * IMGW + xc1) << 5];
      float v10 = (float)vbase[(size_t)(yc1 * IMGW + xc0) << 5];
      float v11 = (float)vbase[(size_t)(yc1 * IMGW + xc1) << 5];
      float s = w00 * v00 + w01 * v01 + w10 * v10 + w11 * v11;
      acc = fmaf(w4[p], s, acc);
    }
  }
  ms[(size_t)q * 256 + t] = 0.5f * acc;  // mean over NBQ=2
}

extern "C" void kernel_launch(void* const* d_in, const int* in_sizes, int n_in,
                              void* d_out, int out_size, void* d_ws, size_t ws_size,
                              hipStream_t stream) {
  const float* query = (const float*)d_in[0];   // (1, 40000, 256)
  const float* value = (const float*)d_in[1];   // (1, 80000, 256)
  const float* ref   = (const float*)d_in[2];   // (1, 40000, 1, 2)
  const float* Wv  = (const float*)d_in[4];
  const float* bv  = (const float*)d_in[5];
  const float* Wso = (const float*)d_in[6];
  const float* bso = (const float*)d_in[7];
  const float* Waw = (const float*)d_in[8];
  const float* baw = (const float*)d_in[9];
  const float* Wo  = (const float*)d_in[10];
  const float* bo  = (const float*)d_in[11];
  float* out = (float*)d_out;

  char* p = (char*)d_ws;
  bf16*  vws    = (bf16*)p;  p += (size_t)2 * 8 * HW_ * 32 * 2;  // 40.96 MB
  float* off_ws = (float*)p; p += (size_t)NQ_ * 128 * 4;         // 20.48 MB
  float* aw_ws  = (float*)p; p += (size_t)NQ_ * 64 * 4;          // 10.24 MB
  float* ms     = (float*)p; p += (size_t)NQ_ * 256 * 4;         // 40.96 MB
  bf16*  BtV    = (bf16*)p;  p += (size_t)256 * 256 * 2;
  bf16*  BtOA   = (bf16*)p;  p += (size_t)192 * 512 * 2;
  bf16*  BtO    = (bf16*)p;  p += (size_t)256 * 256 * 2;

  // weight cast+transpose (tiny)
  cast_transpose_kernel<<<(256 * 256 + 255) / 256, 256, 0, stream>>>(Wv, BtV, 256, 256, 256);
  cast_transpose_kernel<<<(512 * 128 + 255) / 256, 256, 0, stream>>>(Wso, BtOA, 512, 128, 512);
  cast_transpose_kernel<<<(512 * 64 + 255) / 256, 256, 0, stream>>>(Waw, BtOA + (size_t)128 * 512, 512, 64, 512);
  cast_transpose_kernel<<<(256 * 256 + 255) / 256, 256, 0, stream>>>(Wo, BtO, 256, 256, 256);

  // vproj: (80000x256) @ (256x256) -> bf16 (2,8,40000,32)
  mfma_gemm_kernel<256, 0><<<dim3(2, 625), 256, 0, stream>>>(
      value, nullptr, BtV, bv, nullptr, nullptr, vws, nullptr, 2 * HW_, 256);
  // offaw: qe(40000x512) @ (512x192) -> off_ws / aw_ws
  mfma_gemm_kernel<512, 1><<<dim3(2, 313), 256, 0, stream>>>(
      value, query, BtOA, bso, baw, nullptr, off_ws, aw_ws, NQ_, 192);
  // sampling
  deform_attn_kernel<<<dim3(NQ_), 256, 0, stream>>>(vws, off_ws, aw_ws, ref, ms);
  // out: (40000x256) @ (256x256) + b + residual
  mfma_gemm_kernel<256, 2><<<dim3(2, 313), 256, 0, stream>>>(
      ms, nullptr, BtO, bo, nullptr, query, out, nullptr, NQ_, 256);
}

// Round 3
// 340.104 us; speedup vs baseline: 1.7070x; 1.0724x over previous
//
#include <hip/hip_runtime.h>
#include <math.h>

#define HW_   40000      // H*W = 200*200
#define NQ_   40000
#define IMGW  200
#define IMGH  200

typedef __bf16 bf16;
typedef __attribute__((ext_vector_type(4))) __bf16 bf16x4;
typedef __attribute__((ext_vector_type(8))) __bf16 bf16x8;
typedef __attribute__((ext_vector_type(4))) float f32x4;

__device__ __forceinline__ void gload_lds16(const void* g, void* l) {
  __builtin_amdgcn_global_load_lds(
      (const __attribute__((address_space(1))) void*)g,
      (__attribute__((address_space(3))) void*)l, 16, 0, 0);
}

// ---- cast fp32 -> bf16, 8 elems/thread ------------------------------------
__global__ __launch_bounds__(256) void cast_f32_bf16_kernel(
    const float* __restrict__ src, bf16* __restrict__ dst, int n8)
{
  int i = blockIdx.x * 256 + threadIdx.x;
  if (i >= n8) return;
  const float4 a = ((const float4*)src)[2 * i];
  const float4 b = ((const float4*)src)[2 * i + 1];
  bf16x8 o = {(bf16)a.x, (bf16)a.y, (bf16)a.z, (bf16)a.w,
              (bf16)b.x, (bf16)b.y, (bf16)b.z, (bf16)b.w};
  *(bf16x8*)&dst[(size_t)i * 8] = o;
}

// ---- weight cast+transpose: Bt[n][k] = (bf16) B[k][n] ----------------------
__global__ __launch_bounds__(256) void cast_transpose_kernel(
    const float* __restrict__ B, bf16* __restrict__ Bt, int K, int N, int ldt)
{
  int idx = blockIdx.x * 256 + threadIdx.x;
  if (idx >= K * N) return;
  int k = idx / N, n = idx - k * N;
  Bt[(size_t)n * ldt + k] = (bf16)B[idx];
}

// ---------------------------------------------------------------------------
// MFMA bf16 GEMM, m97 recipe: 128x128 tile, BK=32, unpadded LDS (rows 64 B),
// global_load_lds width-16 staging, 4 waves x (4x4) v_mfma_f32_16x16x32_bf16.
// A is bf16 with row stride 256 (two halves A0/A1 when KT=512). Bt is [N][KT].
// MODE 0: vproj -> bf16 (nbq,h,pix,hd), +bias0
// MODE 1: offaw -> off_bf (n<128,+bias0) / aw_bf (128<=n<192,+bias1), bf16
// MODE 2: out   -> fp32 +bias0 +resid
// ---------------------------------------------------------------------------
template<int KT, int MODE>
__global__ __launch_bounds__(256) void mfma_gemm_kernel(
    const bf16* __restrict__ A0, const bf16* __restrict__ A1,
    const bf16* __restrict__ Bt,
    const float* __restrict__ bias0, const float* __restrict__ bias1,
    const float* __restrict__ resid,
    void* __restrict__ outp, void* __restrict__ outp2,
    int M, int N)
{
  __shared__ bf16 As[128 * 32];   // 8 KB, row = 32 bf16 = 64 B, NO pad
  __shared__ bf16 Bs[128 * 32];
  const int t    = threadIdx.x;
  const int m0   = blockIdx.y * 128;
  const int n0   = blockIdx.x * 128;
  const int w    = t >> 6;
  const int lane = t & 63;
  const int quad = lane >> 4;
  const int l16  = lane & 15;
  const int wm   = (w & 1) * 64;
  const int wn   = (w >> 1) * 64;

  f32x4 acc[4][4] = {};

  // staging: each thread copies one 16-B chunk per issue; LDS offset == t*16 B
  const int srow  = t >> 2;        // 0..63
  const int skoff = (t & 3) * 8;   // 0,8,16,24 (elems)
  bf16* ldsA0 = As + t * 8;
  bf16* ldsA1 = As + 2048 + t * 8;
  bf16* ldsB0 = Bs + t * 8;
  bf16* ldsB1 = Bs + 2048 + t * 8;

  int gmA0 = m0 + srow;      if (gmA0 >= M) gmA0 = M - 1;
  int gmA1 = m0 + 64 + srow; if (gmA1 >= M) gmA1 = M - 1;
  int gnB0 = n0 + srow;      if (gnB0 >= N) gnB0 = N - 1;
  int gnB1 = n0 + 64 + srow; if (gnB1 >= N) gnB1 = N - 1;

  for (int kt = 0; kt < KT; kt += 32) {
    const bf16* Ap;
    int col;
    if (KT == 512) { Ap = (kt < 256) ? A0 : A1; col = kt & 255; }
    else           { Ap = A0; col = kt; }
    __syncthreads();
    gload_lds16(&Ap[(size_t)gmA0 * 256 + col + skoff], ldsA0);
    gload_lds16(&Ap[(size_t)gmA1 * 256 + col + skoff], ldsA1);
    gload_lds16(&Bt[(size_t)gnB0 * KT + kt + skoff], ldsB0);
    gload_lds16(&Bt[(size_t)gnB1 * KT + kt + skoff], ldsB1);
    __syncthreads();

    bf16x8 af[4], bfr[4];
#pragma unroll
    for (int x = 0; x < 4; ++x) {
      af[x]  = *(const bf16x8*)&As[(wm + x * 16 + l16) * 32 + quad * 8];
      bfr[x] = *(const bf16x8*)&Bs[(wn + x * 16 + l16) * 32 + quad * 8];
    }
#pragma unroll
    for (int mt = 0; mt < 4; ++mt)
#pragma unroll
      for (int nt = 0; nt < 4; ++nt)
        acc[mt][nt] = __builtin_amdgcn_mfma_f32_16x16x32_bf16(
            af[mt], bfr[nt], acc[mt][nt], 0, 0, 0);
  }

  // ---- epilogue (D: col = lane&15, row = quad*4 + reg) ----
#pragma unroll
  for (int mt = 0; mt < 4; ++mt) {
#pragma unroll
    for (int r = 0; r < 4; ++r) {
      const int gm = m0 + wm + mt * 16 + quad * 4 + r;
      if (gm >= M) continue;
#pragma unroll
      for (int nt = 0; nt < 4; ++nt) {
        const int gn = n0 + wn + nt * 16 + l16;
        float v = acc[mt][nt][r];
        if (MODE == 0) {
          int nbq = (gm >= HW_) ? 1 : 0;
          int pix = gm - nbq * HW_;
          int h = gn >> 5, hd = gn & 31;
          ((bf16*)outp)[(((size_t)(nbq * 8 + h) * HW_ + pix) << 5) + hd] =
              (bf16)(v + bias0[gn]);
        } else if (MODE == 1) {
          if (gn < 128)
            ((bf16*)outp)[(size_t)gm * 128 + gn] = (bf16)(v + bias0[gn]);
          else if (gn < 192)
            ((bf16*)outp2)[(size_t)gm * 64 + (gn - 128)] =
                (bf16)(v + bias1[gn - 128]);
        } else {
          ((float*)outp)[(size_t)gm * 256 + gn] =
              v + bias0[gn] + resid[(size_t)gm * 256 + gn];
        }
      }
    }
  }
}

// ---------------------------------------------------------------------------
// Deform sampling: ONE WAVE per query, 4 queries per block.
// lane = g*4 + sub: g = h*2 + nbq in [0,16), sub in [0,4) covers hd = sub*8..+7
// via bf16x8 16-B gathers. Scalar math shared by only 4 lanes; nbq-pairs
// reduced with shfl_xor(4). Writes ms as bf16 (A-input of the out GEMM).
// ---------------------------------------------------------------------------
__global__ __launch_bounds__(256) void deform_attn_kernel(
    const bf16* __restrict__ vws,     // (2,8,40000,32) bf16
    const bf16* __restrict__ off_bf,  // (40000,128) bf16
    const bf16* __restrict__ aw_bf,   // (40000,64) bf16
    const float* __restrict__ ref,    // (40000,2)
    bf16* __restrict__ ms)            // (40000,256) bf16
{
  const int t    = threadIdx.x;
  const int w    = t >> 6;
  const int lane = t & 63;
  const int q    = blockIdx.x * 4 + w;
  const int g    = lane >> 2;
  const int sub  = lane & 3;
  const int h    = g >> 1;
  const int nbq  = g & 1;

  const float rx = ref[2 * q + 0] * (float)IMGW - 0.5f;
  const float ry = ref[2 * q + 1] * (float)IMGH - 0.5f;

  // softmax over 4 points
  bf16x4 a4 = *(const bf16x4*)&aw_bf[(size_t)q * 64 + g * 4];
  float aa0 = (float)a4[0], aa1 = (float)a4[1], aa2 = (float)a4[2], aa3 = (float)a4[3];
  float mx = fmaxf(fmaxf(aa0, aa1), fmaxf(aa2, aa3));
  float e0 = __expf(aa0 - mx), e1 = __expf(aa1 - mx);
  float e2 = __expf(aa2 - mx), e3 = __expf(aa3 - mx);
  float inv = 1.0f / (e0 + e1 + e2 + e3);
  float w4[4] = {e0 * inv, e1 * inv, e2 * inv, e3 * inv};

  bf16x8 o8 = *(const bf16x8*)&off_bf[(size_t)q * 128 + g * 8];
  float ox[4] = {(float)o8[0], (float)o8[2], (float)o8[4], (float)o8[6]};
  float oy[4] = {(float)o8[1], (float)o8[3], (float)o8[5], (float)o8[7]};

  const bf16* vbase = vws + (((size_t)(nbq * 8 + h) * HW_) << 5) + sub * 8;

  float acc[8] = {};
#pragma unroll
  for (int p = 0; p < 4; ++p) {
    float x = rx + ox[p];
    float y = ry + oy[p];
    float xf = floorf(x), yf = floorf(y);
    int   x0 = (int)xf,   y0 = (int)yf;
    float lx = x - xf,    ly = y - yf;
    int   x1 = x0 + 1,    y1 = y0 + 1;
    float w00 = (1.0f - lx) * (1.0f - ly);
    float w01 = lx * (1.0f - ly);
    float w10 = (1.0f - lx) * ly;
    float w11 = lx * ly;
    if (x0 < 0 || x0 >= IMGW) { w00 = 0.0f; w10 = 0.0f; }
    if (x1 < 0 || x1 >= IMGW) { w01 = 0.0f; w11 = 0.0f; }
    if (y0 < 0 || y0 >= IMGH) { w00 = 0.0f; w01 = 0.0f; }
    if (y1 < 0 || y1 >= IMGH) { w10 = 0.0f; w11 = 0.0f; }
    int xc0 = min(max(x0, 0), IMGW - 1), xc1 = min(max(x1, 0), IMGW - 1);
    int yc0 = min(max(y0, 0), IMGH - 1), yc1 = min(max(y1, 0), IMGH - 1);
    bf16x8 v00 = *(const bf16x8*)&vbase[(size_t)(yc0 * IMGW + xc0) << 5];
    bf16x8 v01 = *(const bf16x8*)&vbase[(size_t)(yc0 * IMGW + xc1) << 5];
    bf16x8 v10 = *(const bf16x8*)&vbase[(size_t)(yc1 * IMGW + xc0) << 5];
    bf16x8 v11 = *(const bf16x8*)&vbase[(size_t)(yc1 * IMGW + xc1) << 5];
    float wp = w4[p];
#pragma unroll
    for (int j = 0; j < 8; ++j) {
      float s = w00 * (float)v00[j] + w01 * (float)v01[j] +
                w10 * (float)v10[j] + w11 * (float)v11[j];
      acc[j] = fmaf(wp, s, acc[j]);
    }
  }

  // reduce the nbq pair (lanes differ by 4)
#pragma unroll
  for (int j = 0; j < 8; ++j) acc[j] += __shfl_xor(acc[j], 4);

  if (nbq == 0) {
    bf16x8 o;
#pragma unroll
    for (int j = 0; j < 8; ++j) o[j] = (bf16)(0.5f * acc[j]);
    *(bf16x8*)&ms[(size_t)q * 256 + h * 32 + sub * 8] = o;
  }
}

extern "C" void kernel_launch(void* const* d_in, const int* in_sizes, int n_in,
                              void* d_out, int out_size, void* d_ws, size_t ws_size,
                              hipStream_t stream) {
  const float* query = (const float*)d_in[0];   // (1, 40000, 256)
  const float* value = (const float*)d_in[1];   // (1, 80000, 256)
  const float* ref   = (const float*)d_in[2];   // (1, 40000, 1, 2)
  const float* Wv  = (const float*)d_in[4];
  const float* bv  = (const float*)d_in[5];
  const float* Wso = (const float*)d_in[6];
  const float* bso = (const float*)d_in[7];
  const float* Waw = (const float*)d_in[8];
  const float* baw = (const float*)d_in[9];
  const float* Wo  = (const float*)d_in[10];
  const float* bo  = (const float*)d_in[11];
  float* out = (float*)d_out;

  char* p = (char*)d_ws;
  bf16* vws    = (bf16*)p; p += (size_t)2 * 8 * HW_ * 32 * 2;   // 40.96 MB
  bf16* off_bf = (bf16*)p; p += (size_t)NQ_ * 128 * 2;          // 10.24 MB
  bf16* aw_bf  = (bf16*)p; p += (size_t)NQ_ * 64 * 2;           //  5.12 MB
  bf16* ms     = (bf16*)p; p += (size_t)NQ_ * 256 * 2;          // 20.48 MB
  bf16* vbf    = (bf16*)p; p += (size_t)2 * HW_ * 256 * 2;      // 40.96 MB
  bf16* qbf    = (bf16*)p; p += (size_t)NQ_ * 256 * 2;          // 20.48 MB
  bf16* BtV    = (bf16*)p; p += (size_t)256 * 256 * 2;
  bf16* BtOA   = (bf16*)p; p += (size_t)192 * 512 * 2;
  bf16* BtO    = (bf16*)p; p += (size_t)256 * 256 * 2;
  // total ~138.8 MB

  // input casts (pure-BW)
  cast_f32_bf16_kernel<<<10000, 256, 0, stream>>>(value, vbf, 2 * HW_ * 256 / 8);
  cast_f32_bf16_kernel<<<5000, 256, 0, stream>>>(query, qbf, NQ_ * 256 / 8);
  // weight cast+transpose (tiny)
  cast_transpose_kernel<<<256, 256, 0, stream>>>(Wv, BtV, 256, 256, 256);
  cast_transpose_kernel<<<256, 256, 0, stream>>>(Wso, BtOA, 512, 128, 512);
  cast_transpose_kernel<<<128, 256, 0, stream>>>(Waw, BtOA + (size_t)128 * 512, 512, 64, 512);
  cast_transpose_kernel<<<256, 256, 0, stream>>>(Wo, BtO, 256, 256, 256);

  // vproj: (80000x256) @ (256x256) -> bf16 (2,8,40000,32)
  mfma_gemm_kernel<256, 0><<<dim3(2, 625), 256, 0, stream>>>(
      vbf, nullptr, BtV, bv, nullptr, nullptr, vws, nullptr, 2 * HW_, 256);
  // offaw: qe(40000x512) @ (512x192) -> off_bf / aw_bf
  mfma_gemm_kernel<512, 1><<<dim3(2, 313), 256, 0, stream>>>(
      vbf, qbf, BtOA, bso, baw, nullptr, off_bf, aw_bf, NQ_, 192);
  // sampling (one wave per query)
  deform_attn_kernel<<<10000, 256, 0, stream>>>(vws, off_bf, aw_bf, ref, ms);
  // out: (40000x256) @ (256x256) + b + residual
  mfma_gemm_kernel<256, 2><<<dim3(2, 313), 256, 0, stream>>>(
      ms, nullptr, BtO, bo, nullptr, query, out, nullptr, NQ_, 256);
}

// Round 4
// 332.034 us; speedup vs baseline: 1.7485x; 1.0243x over previous
//
#include <hip/hip_runtime.h>
#include <math.h>

#define HW_   40000      // H*W = 200*200
#define NQ_   40000
#define IMGW  200
#define IMGH  200

typedef __bf16 bf16;
typedef __attribute__((ext_vector_type(4))) __bf16 bf16x4;
typedef __attribute__((ext_vector_type(8))) __bf16 bf16x8;
typedef __attribute__((ext_vector_type(4))) float f32x4;

__device__ __forceinline__ void gload_lds16(const void* g, void* l) {
  __builtin_amdgcn_global_load_lds(
      (const __attribute__((address_space(1))) void*)g,
      (__attribute__((address_space(3))) void*)l, 16, 0, 0);
}

// ---------------------------------------------------------------------------
// One consolidated prep kernel:
//   blocks [0, 10000)        : value fp32 -> vbf  (8 elems/thread, 20.48M)
//   blocks [10000, 15000)    : query fp32 -> qbf  (8 elems/thread, 10.24M)
//   blocks [15000, 15896)    : weight cast+transpose (scalar, 229376 elems)
// ---------------------------------------------------------------------------
__global__ __launch_bounds__(256) void prep_kernel(
    const float* __restrict__ value, const float* __restrict__ query,
    const float* __restrict__ Wv, const float* __restrict__ Wso,
    const float* __restrict__ Waw, const float* __restrict__ Wo,
    bf16* __restrict__ vbf, bf16* __restrict__ qbf,
    bf16* __restrict__ BtV, bf16* __restrict__ BtOA, bf16* __restrict__ BtO)
{
  const int b = blockIdx.x;
  if (b < 15000) {
    const float* src = (b < 10000) ? value : query;
    bf16* dst        = (b < 10000) ? vbf : qbf;
    int i = (b < 10000 ? b : b - 10000) * 256 + threadIdx.x;
    const float4 a = ((const float4*)src)[2 * i];
    const float4 c = ((const float4*)src)[2 * i + 1];
    bf16x8 o = {(bf16)a.x, (bf16)a.y, (bf16)a.z, (bf16)a.w,
                (bf16)c.x, (bf16)c.y, (bf16)c.z, (bf16)c.w};
    *(bf16x8*)&dst[(size_t)i * 8] = o;
    return;
  }
  int idx = (b - 15000) * 256 + threadIdx.x;
  // Wv: 65536 -> BtV[n*256+k]; Wso: 65536 -> BtOA[n*512+k];
  // Waw: 32768 -> BtOA[(128+n)*512+k]; Wo: 65536 -> BtO[n*256+k]
  if (idx < 65536) {
    int k = idx >> 8, n = idx & 255;
    BtV[(size_t)n * 256 + k] = (bf16)Wv[idx];
  } else if (idx < 131072) {
    int j = idx - 65536;
    int k = j >> 7, n = j & 127;
    BtOA[(size_t)n * 512 + k] = (bf16)Wso[j];
  } else if (idx < 163840) {
    int j = idx - 131072;
    int k = j >> 6, n = j & 63;
    BtOA[(size_t)(128 + n) * 512 + k] = (bf16)Waw[j];
  } else if (idx < 229376) {
    int j = idx - 163840;
    int k = j >> 8, n = j & 255;
    BtO[(size_t)n * 256 + k] = (bf16)Wo[j];
  }
}

// ---------------------------------------------------------------------------
// MFMA bf16 GEMM, software-pipelined: 128x128 tile, BK=32, DOUBLE-buffered
// unpadded LDS (8 KB per buf per operand), global_load_lds width-16, ONE
// barrier per iteration; next tile's loads issued after the barrier and
// before the MFMA block so the vmcnt drain overlaps compute.
// 4 waves x (4x4) v_mfma_f32_16x16x32_bf16.
// MODE 0: vproj -> bf16 (nbq,h,pix,hd), +bias0
// MODE 1: offaw -> off_bf (n<128,+bias0) / aw_bf (128<=n<192,+bias1), bf16
// MODE 2: out   -> fp32 +bias0 +resid
// ---------------------------------------------------------------------------
template<int KT, int MODE>
__global__ __launch_bounds__(256, 4) void mfma_gemm_kernel(
    const bf16* __restrict__ A0, const bf16* __restrict__ A1,
    const bf16* __restrict__ Bt,
    const float* __restrict__ bias0, const float* __restrict__ bias1,
    const float* __restrict__ resid,
    void* __restrict__ outp, void* __restrict__ outp2,
    int M, int N)
{
  __shared__ bf16 As[2][128 * 32];   // 2 x 8 KB
  __shared__ bf16 Bs[2][128 * 32];
  const int t    = threadIdx.x;
  const int m0   = blockIdx.y * 128;
  const int n0   = blockIdx.x * 128;
  const int w    = t >> 6;
  const int lane = t & 63;
  const int quad = lane >> 4;
  const int l16  = lane & 15;
  const int wm   = (w & 1) * 64;
  const int wn   = (w >> 1) * 64;

  f32x4 acc[4][4] = {};

  const int srow  = t >> 2;        // 0..63
  const int skoff = (t & 3) * 8;   // 0,8,16,24 (elems)

  int gmA0 = m0 + srow;      if (gmA0 >= M) gmA0 = M - 1;
  int gmA1 = m0 + 64 + srow; if (gmA1 >= M) gmA1 = M - 1;
  int gnB0 = n0 + srow;      if (gnB0 >= N) gnB0 = N - 1;
  int gnB1 = n0 + 64 + srow; if (gnB1 >= N) gnB1 = N - 1;

  auto issue = [&](int kt, int buf) {
    const bf16* Ap;
    int col;
    if (KT == 512) { Ap = (kt < 256) ? A0 : A1; col = kt & 255; }
    else           { Ap = A0; col = kt; }
    gload_lds16(&Ap[(size_t)gmA0 * 256 + col + skoff], &As[buf][t * 8]);
    gload_lds16(&Ap[(size_t)gmA1 * 256 + col + skoff], &As[buf][2048 + t * 8]);
    gload_lds16(&Bt[(size_t)gnB0 * KT + kt + skoff], &Bs[buf][t * 8]);
    gload_lds16(&Bt[(size_t)gnB1 * KT + kt + skoff], &Bs[buf][2048 + t * 8]);
  };

  constexpr int NIT = KT / 32;
  issue(0, 0);
#pragma unroll
  for (int it = 0; it < NIT; ++it) {
    __syncthreads();                      // drains tile-it loads (vmcnt+barrier)
    if (it + 1 < NIT) issue((it + 1) * 32, (it + 1) & 1);  // overlaps MFMAs below
    const bf16* as = As[it & 1];
    const bf16* bs = Bs[it & 1];
    bf16x8 af[4], bfr[4];
#pragma unroll
    for (int x = 0; x < 4; ++x) {
      af[x]  = *(const bf16x8*)&as[(wm + x * 16 + l16) * 32 + quad * 8];
      bfr[x] = *(const bf16x8*)&bs[(wn + x * 16 + l16) * 32 + quad * 8];
    }
#pragma unroll
    for (int mt = 0; mt < 4; ++mt)
#pragma unroll
      for (int nt = 0; nt < 4; ++nt)
        acc[mt][nt] = __builtin_amdgcn_mfma_f32_16x16x32_bf16(
            af[mt], bfr[nt], acc[mt][nt], 0, 0, 0);
  }

  // ---- epilogue (D: col = lane&15, row = quad*4 + reg) ----
#pragma unroll
  for (int mt = 0; mt < 4; ++mt) {
#pragma unroll
    for (int r = 0; r < 4; ++r) {
      const int gm = m0 + wm + mt * 16 + quad * 4 + r;
      if (gm >= M) continue;
#pragma unroll
      for (int nt = 0; nt < 4; ++nt) {
        const int gn = n0 + wn + nt * 16 + l16;
        float v = acc[mt][nt][r];
        if (MODE == 0) {
          int nbq = (gm >= HW_) ? 1 : 0;
          int pix = gm - nbq * HW_;
          int h = gn >> 5, hd = gn & 31;
          ((bf16*)outp)[(((size_t)(nbq * 8 + h) * HW_ + pix) << 5) + hd] =
              (bf16)(v + bias0[gn]);
        } else if (MODE == 1) {
          if (gn < 128)
            ((bf16*)outp)[(size_t)gm * 128 + gn] = (bf16)(v + bias0[gn]);
          else if (gn < 192)
            ((bf16*)outp2)[(size_t)gm * 64 + (gn - 128)] =
                (bf16)(v + bias1[gn - 128]);
        } else {
          ((float*)outp)[(size_t)gm * 256 + gn] =
              v + bias0[gn] + resid[(size_t)gm * 256 + gn];
        }
      }
    }
  }
}

// ---------------------------------------------------------------------------
// Deform sampling: ONE WAVE per query, 4 queries per block. (unchanged)
// lane = g*4 + sub: g = h*2 + nbq in [0,16), sub in [0,4) covers hd = sub*8..+7
// ---------------------------------------------------------------------------
__global__ __launch_bounds__(256) void deform_attn_kernel(
    const bf16* __restrict__ vws,     // (2,8,40000,32) bf16
    const bf16* __restrict__ off_bf,  // (40000,128) bf16
    const bf16* __restrict__ aw_bf,   // (40000,64) bf16
    const float* __restrict__ ref,    // (40000,2)
    bf16* __restrict__ ms)            // (40000,256) bf16
{
  const int t    = threadIdx.x;
  const int w    = t >> 6;
  const int lane = t & 63;
  const int q    = blockIdx.x * 4 + w;
  const int g    = lane >> 2;
  const int sub  = lane & 3;
  const int h    = g >> 1;
  const int nbq  = g & 1;

  const float rx = ref[2 * q + 0] * (float)IMGW - 0.5f;
  const float ry = ref[2 * q + 1] * (float)IMGH - 0.5f;

  bf16x4 a4 = *(const bf16x4*)&aw_bf[(size_t)q * 64 + g * 4];
  float aa0 = (float)a4[0], aa1 = (float)a4[1], aa2 = (float)a4[2], aa3 = (float)a4[3];
  float mx = fmaxf(fmaxf(aa0, aa1), fmaxf(aa2, aa3));
  float e0 = __expf(aa0 - mx), e1 = __expf(aa1 - mx);
  float e2 = __expf(aa2 - mx), e3 = __expf(aa3 - mx);
  float inv = 1.0f / (e0 + e1 + e2 + e3);
  float w4[4] = {e0 * inv, e1 * inv, e2 * inv, e3 * inv};

  bf16x8 o8 = *(const bf16x8*)&off_bf[(size_t)q * 128 + g * 8];
  float ox[4] = {(float)o8[0], (float)o8[2], (float)o8[4], (float)o8[6]};
  float oy[4] = {(float)o8[1], (float)o8[3], (float)o8[5], (float)o8[7]};

  const bf16* vbase = vws + (((size_t)(nbq * 8 + h) * HW_) << 5) + sub * 8;

  float acc[8] = {};
#pragma unroll
  for (int p = 0; p < 4; ++p) {
    float x = rx + ox[p];
    float y = ry + oy[p];
    float xf = floorf(x), yf = floorf(y);
    int   x0 = (int)xf,   y0 = (int)yf;
    float lx = x - xf,    ly = y - yf;
    int   x1 = x0 + 1,    y1 = y0 + 1;
    float w00 = (1.0f - lx) * (1.0f - ly);
    float w01 = lx * (1.0f - ly);
    float w10 = (1.0f - lx) * ly;
    float w11 = lx * ly;
    if (x0 < 0 || x0 >= IMGW) { w00 = 0.0f; w10 = 0.0f; }
    if (x1 < 0 || x1 >= IMGW) { w01 = 0.0f; w11 = 0.0f; }
    if (y0 < 0 || y0 >= IMGH) { w00 = 0.0f; w01 = 0.0f; }
    if (y1 < 0 || y1 >= IMGH) { w10 = 0.0f; w11 = 0.0f; }
    int xc0 = min(max(x0, 0), IMGW - 1), xc1 = min(max(x1, 0), IMGW - 1);
    int yc0 = min(max(y0, 0), IMGH - 1), yc1 = min(max(y1, 0), IMGH - 1);
    bf16x8 v00 = *(const bf16x8*)&vbase[(size_t)(yc0 * IMGW + xc0) << 5];
    bf16x8 v01 = *(const bf16x8*)&vbase[(size_t)(yc0 * IMGW + xc1) << 5];
    bf16x8 v10 = *(const bf16x8*)&vbase[(size_t)(yc1 * IMGW + xc0) << 5];
    bf16x8 v11 = *(const bf16x8*)&vbase[(size_t)(yc1 * IMGW + xc1) << 5];
    float wp = w4[p];
#pragma unroll
    for (int j = 0; j < 8; ++j) {
      float s = w00 * (float)v00[j] + w01 * (float)v01[j] +
                w10 * (float)v10[j] + w11 * (float)v11[j];
      acc[j] = fmaf(wp, s, acc[j]);
    }
  }

#pragma unroll
  for (int j = 0; j < 8; ++j) acc[j] += __shfl_xor(acc[j], 4);

  if (nbq == 0) {
    bf16x8 o;
#pragma unroll
    for (int j = 0; j < 8; ++j) o[j] = (bf16)(0.5f * acc[j]);
    *(bf16x8*)&ms[(size_t)q * 256 + h * 32 + sub * 8] = o;
  }
}

extern "C" void kernel_launch(void* const* d_in, const int* in_sizes, int n_in,
                              void* d_out, int out_size, void* d_ws, size_t ws_size,
                              hipStream_t stream) {
  const float* query = (const float*)d_in[0];   // (1, 40000, 256)
  const float* value = (const float*)d_in[1];   // (1, 80000, 256)
  const float* ref   = (const float*)d_in[2];   // (1, 40000, 1, 2)
  const float* Wv  = (const float*)d_in[4];
  const float* bv  = (const float*)d_in[5];
  const float* Wso = (const float*)d_in[6];
  const float* bso = (const float*)d_in[7];
  const float* Waw = (const float*)d_in[8];
  const float* baw = (const float*)d_in[9];
  const float* Wo  = (const float*)d_in[10];
  const float* bo  = (const float*)d_in[11];
  float* out = (float*)d_out;

  char* p = (char*)d_ws;
  bf16* vws    = (bf16*)p; p += (size_t)2 * 8 * HW_ * 32 * 2;   // 40.96 MB
  bf16* off_bf = (bf16*)p; p += (size_t)NQ_ * 128 * 2;          // 10.24 MB
  bf16* aw_bf  = (bf16*)p; p += (size_t)NQ_ * 64 * 2;           //  5.12 MB
  bf16* ms     = (bf16*)p; p += (size_t)NQ_ * 256 * 2;          // 20.48 MB
  bf16* vbf    = (bf16*)p; p += (size_t)2 * HW_ * 256 * 2;      // 40.96 MB
  bf16* qbf    = (bf16*)p; p += (size_t)NQ_ * 256 * 2;          // 20.48 MB
  bf16* BtV    = (bf16*)p; p += (size_t)256 * 256 * 2;
  bf16* BtOA   = (bf16*)p; p += (size_t)192 * 512 * 2;
  bf16* BtO    = (bf16*)p; p += (size_t)256 * 256 * 2;

  // all casts / transposes in one launch
  prep_kernel<<<15896, 256, 0, stream>>>(value, query, Wv, Wso, Waw, Wo,
                                         vbf, qbf, BtV, BtOA, BtO);

  // vproj: (80000x256) @ (256x256) -> bf16 (2,8,40000,32)
  mfma_gemm_kernel<256, 0><<<dim3(2, 625), 256, 0, stream>>>(
      vbf, nullptr, BtV, bv, nullptr, nullptr, vws, nullptr, 2 * HW_, 256);
  // offaw: qe(40000x512) @ (512x192) -> off_bf / aw_bf
  mfma_gemm_kernel<512, 1><<<dim3(2, 313), 256, 0, stream>>>(
      vbf, qbf, BtOA, bso, baw, nullptr, off_bf, aw_bf, NQ_, 192);
  // sampling (one wave per query)
  deform_attn_kernel<<<10000, 256, 0, stream>>>(vws, off_bf, aw_bf, ref, ms);
  // out: (40000x256) @ (256x256) + b + residual
  mfma_gemm_kernel<256, 2><<<dim3(2, 313), 256, 0, stream>>>(
      ms, nullptr, BtO, bo, nullptr, query, out, nullptr, NQ_, 256);
}

// Round 5
// 330.883 us; speedup vs baseline: 1.7546x; 1.0035x over previous
//
#include <hip/hip_runtime.h>
#include <math.h>

#define HW_   40000      // H*W = 200*200
#define NQ_   40000
#define IMGW  200
#define IMGH  200

typedef __bf16 bf16;
typedef __attribute__((ext_vector_type(4))) __bf16 bf16x4;
typedef __attribute__((ext_vector_type(8))) __bf16 bf16x8;
typedef __attribute__((ext_vector_type(4))) float f32x4;

__device__ __forceinline__ void gload_lds16(const void* g, void* l) {
  __builtin_amdgcn_global_load_lds(
      (const __attribute__((address_space(1))) void*)g,
      (__attribute__((address_space(3))) void*)l, 16, 0, 0);
}

// ---------------------------------------------------------------------------
// Consolidated prep: value/query fp32->bf16 + weight cast+transpose.
// ---------------------------------------------------------------------------
__global__ __launch_bounds__(256) void prep_kernel(
    const float* __restrict__ value, const float* __restrict__ query,
    const float* __restrict__ Wv, const float* __restrict__ Wso,
    const float* __restrict__ Waw, const float* __restrict__ Wo,
    bf16* __restrict__ vbf, bf16* __restrict__ qbf,
    bf16* __restrict__ BtV, bf16* __restrict__ BtOA, bf16* __restrict__ BtO)
{
  const int b = blockIdx.x;
  if (b < 15000) {
    const float* src = (b < 10000) ? value : query;
    bf16* dst        = (b < 10000) ? vbf : qbf;
    int i = (b < 10000 ? b : b - 10000) * 256 + threadIdx.x;
    const float4 a = ((const float4*)src)[2 * i];
    const float4 c = ((const float4*)src)[2 * i + 1];
    bf16x8 o = {(bf16)a.x, (bf16)a.y, (bf16)a.z, (bf16)a.w,
                (bf16)c.x, (bf16)c.y, (bf16)c.z, (bf16)c.w};
    *(bf16x8*)&dst[(size_t)i * 8] = o;
    return;
  }
  int idx = (b - 15000) * 256 + threadIdx.x;
  if (idx < 65536) {
    int k = idx >> 8, n = idx & 255;
    BtV[(size_t)n * 256 + k] = (bf16)Wv[idx];
  } else if (idx < 131072) {
    int j = idx - 65536;
    int k = j >> 7, n = j & 127;
    BtOA[(size_t)n * 512 + k] = (bf16)Wso[j];
  } else if (idx < 163840) {
    int j = idx - 131072;
    int k = j >> 6, n = j & 63;
    BtOA[(size_t)(128 + n) * 512 + k] = (bf16)Waw[j];
  } else if (idx < 229376) {
    int j = idx - 163840;
    int k = j >> 8, n = j & 255;
    BtO[(size_t)n * 256 + k] = (bf16)Wo[j];
  }
}

// ---------------------------------------------------------------------------
// MFMA bf16 GEMM: 128 x BN block (BN = FULL output width -> A read once),
// BK=32, double-buffered LDS, global_load_lds width-16, one barrier/iter,
// next tile issued right after the barrier so the drain overlaps 32 MFMAs.
// 4 waves, 2M x 2N; each wave 64 x BN/2 via 4 x (BN/32) 16x16x32 MFMAs.
// MODE 0: vproj -> bf16 (nbq,h,pix,hd), +bias0
// MODE 1: offaw -> off_bf (n<128,+bias0) / aw_bf (n>=128,+bias1), bf16
// MODE 2: out   -> fp32 +bias0 +resid
// ---------------------------------------------------------------------------
template<int KT, int MODE, int BN>
__global__ __launch_bounds__(256) void mfma_gemm_kernel(
    const bf16* __restrict__ A0, const bf16* __restrict__ A1,
    const bf16* __restrict__ Bt,
    const float* __restrict__ bias0, const float* __restrict__ bias1,
    const float* __restrict__ resid,
    void* __restrict__ outp, void* __restrict__ outp2, int M)
{
  constexpr int NT16 = BN / 32;        // n-tiles per wave (8 or 6)
  constexpr int BCH  = BN / 64;        // B 16-B chunks per thread (4 or 3)
  __shared__ bf16 As[2][128 * 32];     // 2 x 8 KB
  __shared__ bf16 Bs[2][BN * 32];      // 2 x 16/12 KB
  const int t    = threadIdx.x;
  const int m0   = blockIdx.x * 128;
  const int w    = t >> 6;
  const int lane = t & 63;
  const int quad = lane >> 4;
  const int l16  = lane & 15;
  const int wm   = (w & 1) * 64;
  const int wn   = (w >> 1) * (BN / 2);

  f32x4 acc[4][NT16] = {};

  // A staging: 2 chunks/thread; chunk c -> row c>>2, koff (c&3)*8
  int gmA[2];
#pragma unroll
  for (int i = 0; i < 2; ++i) {
    int gm = m0 + ((i * 256 + t) >> 2);
    gmA[i] = (gm >= M) ? (M - 1) : gm;
  }

  auto issue = [&](int it) {
    const int kt  = it * 32;
    const int buf = it & 1;
    const bf16* Ap;
    int col;
    if (KT == 512) { Ap = (kt < 256) ? A0 : A1; col = kt & 255; }
    else           { Ap = A0; col = kt; }
#pragma unroll
    for (int i = 0; i < 2; ++i) {
      int c = i * 256 + t;
      gload_lds16(&Ap[(size_t)gmA[i] * 256 + col + (c & 3) * 8], &As[buf][c * 8]);
    }
#pragma unroll
    for (int i = 0; i < BCH; ++i) {
      int c = i * 256 + t;
      gload_lds16(&Bt[(size_t)(c >> 2) * KT + kt + (c & 3) * 8], &Bs[buf][c * 8]);
    }
  };

  constexpr int NIT = KT / 32;
  issue(0);
#pragma unroll
  for (int it = 0; it < NIT; ++it) {
    __syncthreads();                       // drains tile-it loads
    if (it + 1 < NIT) issue(it + 1);       // overlaps the MFMA block below
    const bf16* as = As[it & 1];
    const bf16* bs = Bs[it & 1];
    bf16x8 af[4], bfr[NT16];
#pragma unroll
    for (int x = 0; x < 4; ++x)
      af[x] = *(const bf16x8*)&as[(wm + x * 16 + l16) * 32 + quad * 8];
#pragma unroll
    for (int x = 0; x < NT16; ++x)
      bfr[x] = *(const bf16x8*)&bs[(wn + x * 16 + l16) * 32 + quad * 8];
#pragma unroll
    for (int mt = 0; mt < 4; ++mt)
#pragma unroll
      for (int nt = 0; nt < NT16; ++nt)
        acc[mt][nt] = __builtin_amdgcn_mfma_f32_16x16x32_bf16(
            af[mt], bfr[nt], acc[mt][nt], 0, 0, 0);
  }

  // ---- epilogue (D: col = lane&15, row = quad*4 + reg) ----
#pragma unroll
  for (int mt = 0; mt < 4; ++mt) {
#pragma unroll
    for (int r = 0; r < 4; ++r) {
      const int gm = m0 + wm + mt * 16 + quad * 4 + r;
      if (gm >= M) continue;
#pragma unroll
      for (int nt = 0; nt < NT16; ++nt) {
        const int gn = wn + nt * 16 + l16;
        float v = acc[mt][nt][r];
        if (MODE == 0) {
          int nbq = (gm >= HW_) ? 1 : 0;
          int pix = gm - nbq * HW_;
          int h = gn >> 5, hd = gn & 31;
          ((bf16*)outp)[(((size_t)(nbq * 8 + h) * HW_ + pix) << 5) + hd] =
              (bf16)(v + bias0[gn]);
        } else if (MODE == 1) {
          if (gn < 128)
            ((bf16*)outp)[(size_t)gm * 128 + gn] = (bf16)(v + bias0[gn]);
          else
            ((bf16*)outp2)[(size_t)gm * 64 + (gn - 128)] =
                (bf16)(v + bias1[gn - 128]);
        } else {
          ((float*)outp)[(size_t)gm * 256 + gn] =
              v + bias0[gn] + resid[(size_t)gm * 256 + gn];
        }
      }
    }
  }
}

// ---------------------------------------------------------------------------
// Deform sampling: ONE WAVE per query, 4 queries per block. (unchanged)
// ---------------------------------------------------------------------------
__global__ __launch_bounds__(256) void deform_attn_kernel(
    const bf16* __restrict__ vws,     // (2,8,40000,32) bf16
    const bf16* __restrict__ off_bf,  // (40000,128) bf16
    const bf16* __restrict__ aw_bf,   // (40000,64) bf16
    const float* __restrict__ ref,    // (40000,2)
    bf16* __restrict__ ms)            // (40000,256) bf16
{
  const int t    = threadIdx.x;
  const int w    = t >> 6;
  const int lane = t & 63;
  const int q    = blockIdx.x * 4 + w;
  const int g    = lane >> 2;
  const int sub  = lane & 3;
  const int h    = g >> 1;
  const int nbq  = g & 1;

  const float rx = ref[2 * q + 0] * (float)IMGW - 0.5f;
  const float ry = ref[2 * q + 1] * (float)IMGH - 0.5f;

  bf16x4 a4 = *(const bf16x4*)&aw_bf[(size_t)q * 64 + g * 4];
  float aa0 = (float)a4[0], aa1 = (float)a4[1], aa2 = (float)a4[2], aa3 = (float)a4[3];
  float mx = fmaxf(fmaxf(aa0, aa1), fmaxf(aa2, aa3));
  float e0 = __expf(aa0 - mx), e1 = __expf(aa1 - mx);
  float e2 = __expf(aa2 - mx), e3 = __expf(aa3 - mx);
  float inv = 1.0f / (e0 + e1 + e2 + e3);
  float w4[4] = {e0 * inv, e1 * inv, e2 * inv, e3 * inv};

  bf16x8 o8 = *(const bf16x8*)&off_bf[(size_t)q * 128 + g * 8];
  float ox[4] = {(float)o8[0], (float)o8[2], (float)o8[4], (float)o8[6]};
  float oy[4] = {(float)o8[1], (float)o8[3], (float)o8[5], (float)o8[7]};

  const bf16* vbase = vws + (((size_t)(nbq * 8 + h) * HW_) << 5) + sub * 8;

  float acc[8] = {};
#pragma unroll
  for (int p = 0; p < 4; ++p) {
    float x = rx + ox[p];
    float y = ry + oy[p];
    float xf = floorf(x), yf = floorf(y);
    int   x0 = (int)xf,   y0 = (int)yf;
    float lx = x - xf,    ly = y - yf;
    int   x1 = x0 + 1,    y1 = y0 + 1;
    float w00 = (1.0f - lx) * (1.0f - ly);
    float w01 = lx * (1.0f - ly);
    float w10 = (1.0f - lx) * ly;
    float w11 = lx * ly;
    if (x0 < 0 || x0 >= IMGW) { w00 = 0.0f; w10 = 0.0f; }
    if (x1 < 0 || x1 >= IMGW) { w01 = 0.0f; w11 = 0.0f; }
    if (y0 < 0 || y0 >= IMGH) { w00 = 0.0f; w01 = 0.0f; }
    if (y1 < 0 || y1 >= IMGH) { w10 = 0.0f; w11 = 0.0f; }
    int xc0 = min(max(x0, 0), IMGW - 1), xc1 = min(max(x1, 0), IMGW - 1);
    int yc0 = min(max(y0, 0), IMGH - 1), yc1 = min(max(y1, 0), IMGH - 1);
    bf16x8 v00 = *(const bf16x8*)&vbase[(size_t)(yc0 * IMGW + xc0) << 5];
    bf16x8 v01 = *(const bf16x8*)&vbase[(size_t)(yc0 * IMGW + xc1) << 5];
    bf16x8 v10 = *(const bf16x8*)&vbase[(size_t)(yc1 * IMGW + xc0) << 5];
    bf16x8 v11 = *(const bf16x8*)&vbase[(size_t)(yc1 * IMGW + xc1) << 5];
    float wp = w4[p];
#pragma unroll
    for (int j = 0; j < 8; ++j) {
      float s = w00 * (float)v00[j] + w01 * (float)v01[j] +
                w10 * (float)v10[j] + w11 * (float)v11[j];
      acc[j] = fmaf(wp, s, acc[j]);
    }
  }

#pragma unroll
  for (int j = 0; j < 8; ++j) acc[j] += __shfl_xor(acc[j], 4);

  if (nbq == 0) {
    bf16x8 o;
#pragma unroll
    for (int j = 0; j < 8; ++j) o[j] = (bf16)(0.5f * acc[j]);
    *(bf16x8*)&ms[(size_t)q * 256 + h * 32 + sub * 8] = o;
  }
}

extern "C" void kernel_launch(void* const* d_in, const int* in_sizes, int n_in,
                              void* d_out, int out_size, void* d_ws, size_t ws_size,
                              hipStream_t stream) {
  const float* query = (const float*)d_in[0];   // (1, 40000, 256)
  const float* value = (const float*)d_in[1];   // (1, 80000, 256)
  const float* ref   = (const float*)d_in[2];   // (1, 40000, 1, 2)
  const float* Wv  = (const float*)d_in[4];
  const float* bv  = (const float*)d_in[5];
  const float* Wso = (const float*)d_in[6];
  const float* bso = (const float*)d_in[7];
  const float* Waw = (const float*)d_in[8];
  const float* baw = (const float*)d_in[9];
  const float* Wo  = (const float*)d_in[10];
  const float* bo  = (const float*)d_in[11];
  float* out = (float*)d_out;

  char* p = (char*)d_ws;
  bf16* vws    = (bf16*)p; p += (size_t)2 * 8 * HW_ * 32 * 2;   // 40.96 MB
  bf16* off_bf = (bf16*)p; p += (size_t)NQ_ * 128 * 2;          // 10.24 MB
  bf16* aw_bf  = (bf16*)p; p += (size_t)NQ_ * 64 * 2;           //  5.12 MB
  bf16* ms     = (bf16*)p; p += (size_t)NQ_ * 256 * 2;          // 20.48 MB
  bf16* vbf    = (bf16*)p; p += (size_t)2 * HW_ * 256 * 2;      // 40.96 MB
  bf16* qbf    = (bf16*)p; p += (size_t)NQ_ * 256 * 2;          // 20.48 MB
  bf16* BtV    = (bf16*)p; p += (size_t)256 * 256 * 2;
  bf16* BtOA   = (bf16*)p; p += (size_t)192 * 512 * 2;
  bf16* BtO    = (bf16*)p; p += (size_t)256 * 256 * 2;

  prep_kernel<<<15896, 256, 0, stream>>>(value, query, Wv, Wso, Waw, Wo,
                                         vbf, qbf, BtV, BtOA, BtO);

  // vproj: (80000x256) @ (256x256) -> bf16 (2,8,40000,32)
  mfma_gemm_kernel<256, 0, 256><<<625, 256, 0, stream>>>(
      vbf, nullptr, BtV, bv, nullptr, nullptr, vws, nullptr, 2 * HW_);
  // offaw: qe(40000x512) @ (512x192) -> off_bf / aw_bf
  mfma_gemm_kernel<512, 1, 192><<<313, 256, 0, stream>>>(
      vbf, qbf, BtOA, bso, baw, nullptr, off_bf, aw_bf, NQ_);
  // sampling (one wave per query)
  deform_attn_kernel<<<10000, 256, 0, stream>>>(vws, off_bf, aw_bf, ref, ms);
  // out: (40000x256) @ (256x256) + b + residual
  mfma_gemm_kernel<256, 2, 256><<<313, 256, 0, stream>>>(
      ms, nullptr, BtO, bo, nullptr, query, out, nullptr, NQ_);
}